// Round 5
// baseline (696.104 us; speedup 1.0000x reference)
//
#include <hip/hip_runtime.h>

// ---------------- dtype helpers ----------------
__device__ __forceinline__ float b2f(unsigned short u) {
  return __uint_as_float(((unsigned)u) << 16);
}
__device__ __forceinline__ unsigned short f2b(float f) {
  unsigned u = __float_as_uint(f);
  return (unsigned short)((u + 0x7FFFu + ((u >> 16) & 1u)) >> 16);
}
// load element i of a tensor that is bf16 (isb=1) or fp32 (isb=0)
__device__ __forceinline__ float gload(const void* p, int i, int isb) {
  return isb ? b2f(((const unsigned short*)p)[i]) : ((const float*)p)[i];
}
// monotone bijection float -> uint32 (order-preserving incl. negatives)
__device__ __forceinline__ unsigned tokey(float f) {
  unsigned u = __float_as_uint(f);
  return u ^ (unsigned)(((int)u >> 31) | 0x80000000u);
}

// ---------------- dtype detector (dataset proven fp32; kept for safety) ----------------
__global__ void k_detect(const void* x, int* flag) {
  int tid = threadIdx.x;  // 1 wave
  unsigned short u = ((const unsigned short*)x)[2 * tid];
  int e = (u >> 7) & 0xFF;
  bool sane = (e >= 100 && e <= 140);
  unsigned long long m = __ballot(sane);
  if (tid == 0) *flag = (__popcll(m) >= 40) ? 1 : 0;
}

// ---------------- k_prep: WtF[i][u] = fc1_w[u][i] * (mask<0.5), f32 transposed ----------------
__global__ __launch_bounds__(256) void k_prep(const void* __restrict__ fc1w,
                                              const void* __restrict__ mraw,
                                              float* __restrict__ WtF,
                                              const int* __restrict__ flag) {
  __shared__ float tile[64][65];
  const int isb = *flag;
  const int i0 = blockIdx.x * 64;  // K index (9216)
  const int u0 = blockIdx.y * 64;  // unit index (1024)
  const int tx = threadIdx.x & 63, ty = threadIdx.x >> 6;
  for (int uu = ty; uu < 64; uu += 4) {
    int gi = (u0 + uu) * 9216 + i0 + tx;
    float wv = gload(fc1w, gi, isb);
    float mv = gload(mraw, gi, isb);
    tile[uu][tx] = (mv < 0.5f) ? wv : 0.0f;
  }
  __syncthreads();
  for (int ii = ty; ii < 64; ii += 4)
    WtF[(i0 + ii) * 1024 + u0 + tx] = tile[tx][ii];
}

// ---------------- k_convf: FAST PATH (fp32 input proven by detector) ----------------
// v4 theory: r3 counters showed Occupancy 33% (LDS 51.2KB caps 3 blocks/CU) and
// per-SIMD VALU busy ~35% (latency-bound on the barrier-heavy select phase), with
// 2.19e7 LDS conflict cycles (same-bin histogram atomics). Changes:
//  - NO img/cw LDS staging: x rows read direct from global (3KB/image, L1-resident,
//    lanes share <=16 distinct 16B addrs per load -> broadcast-coalesced); weights
//    direct from global (L1). Saves 9.5KB LDS + staging barriers/instructions.
//  - hist 4-way -> 2-way split: saves 2KB. LDS total ~39.4KB -> 4 blocks/CU.
//  - pass-3 histogram atomics run-length aggregated (thread's 36 keys share few
//    exponent bins -> ~6 atomics instead of 36: cuts same-bin serialization).
//  - passes 2..0 iterate a surviving-candidate bitmask (few bits) instead of
//    re-testing all 36 keys each pass.
// Conv fmaf chain order, pooled layout, scan and compaction semantics unchanged
// => bit-exact. bf16 inputs handled by the gated fallback kernel below.
__global__ __launch_bounds__(256) void k_convf(const float* __restrict__ x,
                                               const float* __restrict__ c1w,
                                               const float* __restrict__ c1b,
                                               const float* __restrict__ duty,
                                               int2* __restrict__ wpair,
                                               int* __restrict__ wcnt,
                                               const int* __restrict__ flag) {
  if (*flag) return;  // bf16 dataset -> fallback kernel handles it
  __shared__ __align__(16) float pooled[9216];
  __shared__ unsigned hist2[2][256];
  __shared__ float cb[64], bcs[64];
  __shared__ unsigned wtot[4];
  __shared__ unsigned selb, selk;
  const int tid = threadIdx.x;
  const int b = blockIdx.x;
  const int lane = tid & 63;
  const int wv_id = tid >> 6;

  if (tid < 64) {
    cb[tid] = c1b[tid];
    float arg = (float)(400.0 / 9216.0) - duty[tid];
    bcs[tid] = (float)exp((double)arg);
  }
  __syncthreads();

  // mapping: c = tid>>2 (64), half = tid&1 (2), pg = (tid>>1)&1 (2) -> ph0 = pg*6
  {
    const float* __restrict__ imgg = x + b * 784;
    const int c = tid >> 2;
    const int half = tid & 1;
    const int ph0 = ((tid >> 1) & 1) * 6;
    float w[25];
#pragma unroll
    for (int i = 0; i < 25; ++i) w[i] = c1w[c * 25 + i];
    const float bias = cb[c];
    float R[6][16];
#pragma unroll
    for (int r = 0; r < 6; ++r) {
      int ir = 2 * ph0 + r;
#pragma unroll
      for (int q = 0; q < 4; ++q)
        ((float4*)&R[r][0])[q] = ((const float4*)imgg)[ir * 7 + half * 3 + q];
    }
#pragma unroll
    for (int i = 0; i < 6; ++i) {
      const int ph = ph0 + i;
      float a0[12], a1[12];
#pragma unroll
      for (int j = 0; j < 12; ++j) { a0[j] = 0.f; a1[j] = 0.f; }
      // single sequential fmaf chain per conv cell, k = kw*5 + kh order
      // (kh fastest -- Eigen patch linearization) => bit-exact vs reference
#pragma unroll
      for (int kj = 0; kj < 5; ++kj) {       // kw OUTER
#pragma unroll
        for (int kr = 0; kr < 5; ++kr) {     // kh INNER (fastest)
          float wk = w[kr * 5 + kj];
          const float* r0 = &R[(2 * i + kr) % 6][0];
          const float* r1 = &R[(2 * i + kr + 1) % 6][0];
#pragma unroll
          for (int j = 0; j < 12; ++j) {
            a0[j] = fmaf(r0[j + kj], wk, a0[j]);
            a1[j] = fmaf(r1[j + kj], wk, a1[j]);
          }
        }
      }
      int obase = c * 144 + ph * 12 + half * 6;
#pragma unroll
      for (int q = 0; q < 6; ++q) {
        float m = fmaxf(fmaxf(a0[2 * q], a0[2 * q + 1]),
                        fmaxf(a1[2 * q], a1[2 * q + 1]));
        pooled[obase + q] = m + bias;
      }
      if (i < 5) {  // slide: load img rows 2*ph+6, 2*ph+7 over the two oldest
        int ir0 = 2 * ph + 6, ir1 = 2 * ph + 7;
        float* d0 = &R[(2 * i) % 6][0];
        float* d1 = &R[(2 * i + 1) % 6][0];
#pragma unroll
        for (int q = 0; q < 4; ++q) {
          ((float4*)d0)[q] = ((const float4*)imgg)[ir0 * 7 + half * 3 + q];
          ((float4*)d1)[q] = ((const float4*)imgg)[ir1 * 7 + half * 3 + q];
        }
      }
    }
  }
  __syncthreads();

  // this thread's 36 select keys (contiguous flat range [tid*36, tid*36+36))
  unsigned keys[36];
  {
    const float bcf = bcs[tid >> 2];
#pragma unroll
    for (int e4 = 0; e4 < 9; ++e4) {
      float4 pv = ((float4*)pooled)[tid * 9 + e4];
      keys[4 * e4 + 0] = tokey(pv.x * bcf);
      keys[4 * e4 + 1] = tokey(pv.y * bcf);
      keys[4 * e4 + 2] = tokey(pv.z * bcf);
      keys[4 * e4 + 3] = tokey(pv.w * bcf);
    }
  }

  // radix-select the 400th-largest key
  unsigned kfix = 0;
  unsigned kk = 400;
  unsigned long long cand = 0xFFFFFFFFFFFFFFFFull >> 28;  // 36 ones
  for (int pass = 3; pass >= 0; --pass) {
    const int shift = pass * 8;
    const unsigned himask = (pass == 3) ? 0u : (0xFFFFFFFFu << (shift + 8));
    hist2[0][tid] = 0;
    hist2[1][tid] = 0;
    __syncthreads();
    unsigned* myh = hist2[wv_id >> 1];
    if (pass == 3) {
      // run-length aggregated: consecutive keys often share the exponent byte
      unsigned cbin = 0xFFFFFFFFu, ccnt = 0;
#pragma unroll
      for (int e = 0; e < 36; ++e) {
        unsigned bin = keys[e] >> 24;
        if (bin == cbin) {
          ++ccnt;
        } else {
          if (ccnt) atomicAdd(&myh[cbin], ccnt);
          cbin = bin;
          ccnt = 1;
        }
      }
      if (ccnt) atomicAdd(&myh[cbin], ccnt);
    } else {
      unsigned long long m = cand;
      unsigned long long keep = 0;
      while (m) {
        int e = __builtin_ctzll(m);
        m &= m - 1;
        if (((keys[e] ^ kfix) & himask) == 0) {
          atomicAdd(&myh[(keys[e] >> shift) & 255u], 1u);
          keep |= 1ull << e;
        }
      }
      cand = keep;
    }
    __syncthreads();
    unsigned own = hist2[0][tid] + hist2[1][tid];
    unsigned v = own;
#pragma unroll
    for (int off = 1; off < 64; off <<= 1) {
      unsigned y = __shfl_down(v, off, 64);
      if (lane + off < 64) v += y;
    }
    if (lane == 0) wtot[wv_id] = v;
    __syncthreads();
#pragma unroll
    for (int w2 = 0; w2 < 4; ++w2)
      if (w2 > wv_id) v += wtot[w2];
    unsigned snext = v - own;
    if (v >= kk && snext < kk) {
      selb = (unsigned)tid;
      selk = kk - snext;
    }
    __syncthreads();
    kfix |= selb << shift;
    kk = selk;
    __syncthreads();
  }

  // sorted compaction: per-thread count -> shfl prefix scan -> ordered write.
  unsigned mycnt = 0;
#pragma unroll
  for (int e = 0; e < 36; ++e) mycnt += (keys[e] >= kfix) ? 1u : 0u;
  unsigned px = mycnt;
#pragma unroll
  for (int off = 1; off < 64; off <<= 1) {
    unsigned y = __shfl_up(px, off, 64);
    if (lane >= off) px += y;
  }
  if (lane == 63) wtot[wv_id] = px;
  __syncthreads();
  unsigned base = 0;
#pragma unroll
  for (int w2 = 0; w2 < 4; ++w2)
    if (w2 < wv_id) base += wtot[w2];
  int pos = (int)(base + px - mycnt);  // exclusive prefix
  for (int e = 0; e < 36; ++e) {
    if (keys[e] >= kfix) {
      int o = tid * 36 + e;
      if (pos < 512)
        wpair[b * 512 + pos] = make_int2(__float_as_int(pooled[o]), o << 12);
      ++pos;
    }
  }
  if (tid == 0) {
    unsigned tot = wtot[0] + wtot[1] + wtot[2] + wtot[3];
    wcnt[b] = (int)(tot < 512u ? tot : 512u);
  }
}

// ---------------- k_conv: bf16 fallback (gated; dataset proven fp32) ----------------
__global__ __launch_bounds__(256) void k_conv(const void* __restrict__ x,
                                              const void* __restrict__ c1w_g,
                                              const void* __restrict__ c1b_g,
                                              const void* __restrict__ duty_g,
                                              int2* __restrict__ wpair,
                                              int* __restrict__ wcnt,
                                              const int* __restrict__ flag) {
  const int isb = *flag;
  if (!isb) return;  // fast kernel handled it
  __shared__ __align__(16) float img[784];
  __shared__ float cw[1600];
  __shared__ float cb[64], bcs[64];
  __shared__ __align__(16) float pooled[9216];
  __shared__ unsigned hist4[4][256];
  __shared__ unsigned wtot[4];
  __shared__ unsigned selb, selk;
  const int tid = threadIdx.x;
  const int b = blockIdx.x;
  const int lane = tid & 63;
  const int wv_id = tid >> 6;

  for (int i = tid; i < 784; i += 256) img[i] = gload(x, b * 784 + i, isb);
  for (int i = tid; i < 1600; i += 256) cw[i] = gload(c1w_g, i, isb);
  if (tid < 64) {
    cb[tid] = gload(c1b_g, tid, isb);
    float arg = (float)(400.0 / 9216.0) - gload(duty_g, tid, isb);
    bcs[tid] = (float)exp((double)arg);
  }
  __syncthreads();

  {
    const int c = tid >> 2;
    const int half = tid & 1;
    const int ph0 = ((tid >> 1) & 1) * 6;
    float w[25];
#pragma unroll
    for (int i = 0; i < 25; ++i) w[i] = cw[c * 25 + i];
    const float bias = cb[c];
    float R[6][16];
#pragma unroll
    for (int r = 0; r < 6; ++r) {
      int ir = 2 * ph0 + r;
#pragma unroll
      for (int q = 0; q < 4; ++q)
        ((float4*)&R[r][0])[q] = ((const float4*)img)[ir * 7 + half * 3 + q];
    }
#pragma unroll
    for (int i = 0; i < 6; ++i) {
      const int ph = ph0 + i;
      float a0[12], a1[12];
#pragma unroll
      for (int j = 0; j < 12; ++j) { a0[j] = 0.f; a1[j] = 0.f; }
#pragma unroll
      for (int kj = 0; kj < 5; ++kj) {
#pragma unroll
        for (int kr = 0; kr < 5; ++kr) {
          float wk = w[kr * 5 + kj];
          const float* r0 = &R[(2 * i + kr) % 6][0];
          const float* r1 = &R[(2 * i + kr + 1) % 6][0];
#pragma unroll
          for (int j = 0; j < 12; ++j) {
            a0[j] = fmaf(r0[j + kj], wk, a0[j]);
            a1[j] = fmaf(r1[j + kj], wk, a1[j]);
          }
        }
      }
      int obase = c * 144 + ph * 12 + half * 6;
#pragma unroll
      for (int q = 0; q < 6; ++q) {
        float m = fmaxf(fmaxf(a0[2 * q], a0[2 * q + 1]),
                        fmaxf(a1[2 * q], a1[2 * q + 1]));
        pooled[obase + q] = m + bias;
      }
      if (i < 5) {
        int ir0 = 2 * ph + 6, ir1 = 2 * ph + 7;
        float* d0 = &R[(2 * i) % 6][0];
        float* d1 = &R[(2 * i + 1) % 6][0];
#pragma unroll
        for (int q = 0; q < 4; ++q) {
          ((float4*)d0)[q] = ((const float4*)img)[ir0 * 7 + half * 3 + q];
          ((float4*)d1)[q] = ((const float4*)img)[ir1 * 7 + half * 3 + q];
        }
      }
    }
  }
  __syncthreads();

  unsigned keys[36];
  {
    const float bcf = bcs[tid >> 2];
#pragma unroll
    for (int e4 = 0; e4 < 9; ++e4) {
      float4 pv = ((float4*)pooled)[tid * 9 + e4];
      keys[4 * e4 + 0] = tokey(pv.x * bcf);
      keys[4 * e4 + 1] = tokey(pv.y * bcf);
      keys[4 * e4 + 2] = tokey(pv.z * bcf);
      keys[4 * e4 + 3] = tokey(pv.w * bcf);
    }
  }

  unsigned kfix = 0;
  unsigned kk = 400;
  for (int pass = 3; pass >= 0; --pass) {
    const int shift = pass * 8;
    const unsigned himask = (pass == 3) ? 0u : (0xFFFFFFFFu << (shift + 8));
#pragma unroll
    for (int w2 = 0; w2 < 4; ++w2) hist4[w2][tid] = 0;
    __syncthreads();
    unsigned* myh = hist4[wv_id];
#pragma unroll
    for (int e = 0; e < 36; ++e) {
      unsigned key = keys[e];
      if (((key ^ kfix) & himask) == 0)
        atomicAdd(&myh[(key >> shift) & 255u], 1u);
    }
    __syncthreads();
    unsigned own = hist4[0][tid] + hist4[1][tid] + hist4[2][tid] + hist4[3][tid];
    unsigned v = own;
#pragma unroll
    for (int off = 1; off < 64; off <<= 1) {
      unsigned y = __shfl_down(v, off, 64);
      if (lane + off < 64) v += y;
    }
    if (lane == 0) wtot[wv_id] = v;
    __syncthreads();
#pragma unroll
    for (int w2 = 0; w2 < 4; ++w2)
      if (w2 > wv_id) v += wtot[w2];
    unsigned snext = v - own;
    if (v >= kk && snext < kk) {
      selb = (unsigned)tid;
      selk = kk - snext;
    }
    __syncthreads();
    kfix |= selb << shift;
    kk = selk;
    __syncthreads();
  }

  unsigned mycnt = 0;
#pragma unroll
  for (int e = 0; e < 36; ++e) mycnt += (keys[e] >= kfix) ? 1u : 0u;
  unsigned px = mycnt;
#pragma unroll
  for (int off = 1; off < 64; off <<= 1) {
    unsigned y = __shfl_up(px, off, 64);
    if (lane >= off) px += y;
  }
  if (lane == 63) wtot[wv_id] = px;
  __syncthreads();
  unsigned base = 0;
#pragma unroll
  for (int w2 = 0; w2 < 4; ++w2)
    if (w2 < wv_id) base += wtot[w2];
  int pos = (int)(base + px - mycnt);
  for (int e = 0; e < 36; ++e) {
    if (keys[e] >= kfix) {
      int o = tid * 36 + e;
      if (pos < 512)
        wpair[b * 512 + pos] = make_int2(__float_as_int(pooled[o]), o << 12);
      ++pos;
    }
  }
  if (tid == 0) {
    unsigned tot = wtot[0] + wtot[1] + wtot[2] + wtot[3];
    wcnt[b] = (int)(tot < 512u ? tot : 512u);
  }
}

// ---------------- k_fc1: XCD-sliced sparse fc1 gather ----------------
// slice = blockIdx.x & 7 -> consecutive blocks round-robin across the 8 XCDs,
// so each XCD's L2 only sees its 128-unit column slice of WtF (4.7 MB ~ L2).
// LDS-staged winner list; 8-pair unroll via ds_read_b128 so the 8 independent
// global_load_dword issue ahead of the serial fmac chain. Ascending-w single
// f32 fmaf chain per unit => bit-identical h. Half-grid (img_base) x2 for
// rocprof visibility of the other kernels.
__global__ __launch_bounds__(128) void k_fc1(const float* __restrict__ WtF,
                                             const int2* __restrict__ wpair,
                                             const int* __restrict__ wcnt,
                                             const void* __restrict__ fc1b,
                                             float* __restrict__ h,
                                             const int* __restrict__ flag,
                                             int img_base) {
  __shared__ __align__(16) int2 wl[512];
  const int tid = threadIdx.x;  // 0..127
  const int img = img_base + (blockIdx.x >> 3);
  const int slice = blockIdx.x & 7;
  const int isb = *flag;
  const int cnt = wcnt[img];
  const int2* __restrict__ wp = wpair + img * 512;
  for (int i = tid; i < cnt; i += 128) wl[i] = wp[i];
  __syncthreads();
  const int u = (slice << 7) + tid;
  const char* __restrict__ Wb = (const char*)WtF + (unsigned)u * 4u;
  const int4* wl4 = (const int4*)wl;  // 2 pairs per int4, 16B-aligned
  float acc = 0.f;
  int w = 0;
  for (; w + 8 <= cnt; w += 8) {
    const int b4 = w >> 1;
    int4 q0 = wl4[b4 + 0];
    int4 q1 = wl4[b4 + 1];
    int4 q2 = wl4[b4 + 2];
    int4 q3 = wl4[b4 + 3];
    acc = fmaf(__int_as_float(q0.x), *(const float*)(Wb + (unsigned)q0.y), acc);
    acc = fmaf(__int_as_float(q0.z), *(const float*)(Wb + (unsigned)q0.w), acc);
    acc = fmaf(__int_as_float(q1.x), *(const float*)(Wb + (unsigned)q1.y), acc);
    acc = fmaf(__int_as_float(q1.z), *(const float*)(Wb + (unsigned)q1.w), acc);
    acc = fmaf(__int_as_float(q2.x), *(const float*)(Wb + (unsigned)q2.y), acc);
    acc = fmaf(__int_as_float(q2.z), *(const float*)(Wb + (unsigned)q2.w), acc);
    acc = fmaf(__int_as_float(q3.x), *(const float*)(Wb + (unsigned)q3.y), acc);
    acc = fmaf(__int_as_float(q3.z), *(const float*)(Wb + (unsigned)q3.w), acc);
  }
  for (; w < cnt; ++w) {
    int2 p = wl[w];
    acc = fmaf(__int_as_float(p.x), *(const float*)(Wb + (unsigned)p.y), acc);
  }
  h[img * 1024 + u] = acc + gload(fc1b, u, isb);
}

// ---------------- k_boost: fc boost factors computed ONCE ----------------
__global__ __launch_bounds__(256) void k_boost(const void* __restrict__ dutyfc,
                                               float* __restrict__ bf,
                                               const int* __restrict__ flag) {
  const int u = blockIdx.x * 256 + threadIdx.x;
  const int isb = *flag;
  if (u < 1024)
    bf[u] = (float)exp((double)(0.09765625f - gload(dutyfc, u, isb)));
}

// ---------------- k_sel: kwinners(k=100, >=thr) + f64 fc2 + log_softmax ----------------
__global__ __launch_bounds__(256) void k_sel(const float* __restrict__ h,
                                             const float* __restrict__ bf,
                                             const void* __restrict__ fc2w,
                                             const void* __restrict__ fc2b,
                                             void* __restrict__ out,
                                             const int* __restrict__ flag) {
  __shared__ unsigned hist4[4][256];
  __shared__ unsigned wtot[4];
  __shared__ unsigned selb, selk;
  __shared__ double lg[10];
  __shared__ double mred[2];
  const int tid = threadIdx.x;
  const int row = blockIdx.x;
  const int isb = *flag;
  const int lane = tid & 63;
  const int wv_id = tid >> 6;
  if (tid < 10) lg[tid] = (double)gload(fc2b, tid, isb);
  __syncthreads();

  const int u0 = 2 * tid, u1 = 2 * tid + 1, u2 = 512 + 2 * tid, u3 = 513 + 2 * tid;
  float2 hlo = ((const float2*)(h + row * 1024))[tid];
  float2 hhi = ((const float2*)(h + row * 1024 + 512))[tid];
  float h0 = hlo.x, h1 = hlo.y, h2 = hhi.x, h3 = hhi.y;
  float2 blo = ((const float2*)bf)[tid];
  float2 bhi = ((const float2*)(bf + 512))[tid];
  unsigned k0 = tokey(h0 * blo.x);
  unsigned k1 = tokey(h1 * blo.y);
  unsigned k2 = tokey(h2 * bhi.x);
  unsigned k3 = tokey(h3 * bhi.y);

  unsigned kfix = 0;
  unsigned kk = 100;
  for (int pass = 3; pass >= 0; --pass) {
    const int shift = pass * 8;
    const unsigned himask = (pass == 3) ? 0u : (0xFFFFFFFFu << (shift + 8));
#pragma unroll
    for (int w2 = 0; w2 < 4; ++w2) hist4[w2][tid] = 0;
    __syncthreads();
    unsigned* myh = hist4[wv_id];
    if (((k0 ^ kfix) & himask) == 0) atomicAdd(&myh[(k0 >> shift) & 255u], 1u);
    if (((k1 ^ kfix) & himask) == 0) atomicAdd(&myh[(k1 >> shift) & 255u], 1u);
    if (((k2 ^ kfix) & himask) == 0) atomicAdd(&myh[(k2 >> shift) & 255u], 1u);
    if (((k3 ^ kfix) & himask) == 0) atomicAdd(&myh[(k3 >> shift) & 255u], 1u);
    __syncthreads();
    unsigned own = hist4[0][tid] + hist4[1][tid] + hist4[2][tid] + hist4[3][tid];
    unsigned v = own;
#pragma unroll
    for (int off = 1; off < 64; off <<= 1) {
      unsigned y = __shfl_down(v, off, 64);
      if (lane + off < 64) v += y;
    }
    if (lane == 0) wtot[wv_id] = v;
    __syncthreads();
#pragma unroll
    for (int w2 = 0; w2 < 4; ++w2)
      if (w2 > wv_id) v += wtot[w2];
    unsigned snext = v - own;
    if (v >= kk && snext < kk) {
      selb = (unsigned)tid;
      selk = kk - snext;
    }
    __syncthreads();
    kfix |= selb << shift;
    kk = selk;
    __syncthreads();
  }
  bool kp0 = k0 >= kfix, kp1 = k1 >= kfix, kp2 = k2 >= kfix, kp3 = k3 >= kfix;

  double part[10];
#pragma unroll
  for (int c = 0; c < 10; ++c) part[c] = 0.0;
  if (kp0) {
#pragma unroll
    for (int c = 0; c < 10; ++c) part[c] = fma((double)h0, (double)gload(fc2w, c * 1024 + u0, isb), part[c]);
  }
  if (kp1) {
#pragma unroll
    for (int c = 0; c < 10; ++c) part[c] = fma((double)h1, (double)gload(fc2w, c * 1024 + u1, isb), part[c]);
  }
  if (kp2) {
#pragma unroll
    for (int c = 0; c < 10; ++c) part[c] = fma((double)h2, (double)gload(fc2w, c * 1024 + u2, isb), part[c]);
  }
  if (kp3) {
#pragma unroll
    for (int c = 0; c < 10; ++c) part[c] = fma((double)h3, (double)gload(fc2w, c * 1024 + u3, isb), part[c]);
  }
#pragma unroll
  for (int c = 0; c < 10; ++c) {
    double p = part[c];
    for (int off = 32; off > 0; off >>= 1) p += __shfl_xor(p, off);
    if ((tid & 63) == 0) atomicAdd(&lg[c], p);
  }
  __syncthreads();
  if (tid == 0) {
    double m = lg[0];
#pragma unroll
    for (int c = 1; c < 10; ++c) m = lg[c] > m ? lg[c] : m;
    double sum = 0.0;
#pragma unroll
    for (int c = 0; c < 10; ++c) sum += exp(lg[c] - m);
    mred[0] = m;
    mred[1] = log(sum);
  }
  __syncthreads();
  if (tid < 10) {
    double o = lg[tid] - mred[0] - mred[1];
    if (isb)
      ((unsigned short*)out)[row * 10 + tid] = f2b((float)o);
    else
      ((float*)out)[row * 10 + tid] = (float)o;
  }
}

// ---------------- launch ----------------
extern "C" void kernel_launch(void* const* d_in, const int* in_sizes, int n_in,
                              void* d_out, int out_size, void* d_ws, size_t ws_size,
                              hipStream_t stream) {
  // ws layout (bytes):
  //   WtF   : 9216*1024*4 = 37,748,736  @ 0   (reused as bf[1024] after k_fc1)
  //   wpair : 4096*512*8  = 16,777,216  @ 37,748,736
  //   wcnt  : 4096*4      =     16,384  @ 54,525,952
  //   h     : 4096*1024*4 = 16,777,216  @ 54,542,336
  //   flag  : 4                         @ 71,319,552
  char* ws = (char*)d_ws;
  float* WtF = (float*)ws;
  int2* wpair = (int2*)(ws + 37748736);
  int* wcnt = (int*)(ws + 54525952);
  float* h = (float*)(ws + 54542336);
  int* flag = (int*)(ws + 71319552);
  float* bf = WtF;  // WtF region is dead after k_fc1

  k_detect<<<1, 64, 0, stream>>>(d_in[0], flag);
  k_prep<<<dim3(144, 16), 256, 0, stream>>>(d_in[4], d_in[5], WtF, flag);
  k_convf<<<4096, 256, 0, stream>>>((const float*)d_in[0], (const float*)d_in[1],
                                    (const float*)d_in[2], (const float*)d_in[3],
                                    wpair, wcnt, flag);
  k_conv<<<4096, 256, 0, stream>>>(d_in[0], d_in[1], d_in[2], d_in[3],
                                   wpair, wcnt, flag);
  k_fc1<<<2048 * 8, 128, 0, stream>>>(WtF, wpair, wcnt, d_in[6], h, flag, 0);
  k_fc1<<<2048 * 8, 128, 0, stream>>>(WtF, wpair, wcnt, d_in[6], h, flag, 2048);
  k_boost<<<4, 256, 0, stream>>>(d_in[7], bf, flag);
  k_sel<<<4096, 256, 0, stream>>>(h, bf, d_in[8], d_in[9], d_out, flag);
}

// Round 6
// 651.082 us; speedup vs baseline: 1.0691x; 1.0691x over previous
//
#include <hip/hip_runtime.h>

// ---------------- dtype helpers ----------------
__device__ __forceinline__ float b2f(unsigned short u) {
  return __uint_as_float(((unsigned)u) << 16);
}
__device__ __forceinline__ unsigned short f2b(float f) {
  unsigned u = __float_as_uint(f);
  return (unsigned short)((u + 0x7FFFu + ((u >> 16) & 1u)) >> 16);
}
// load element i of a tensor that is bf16 (isb=1) or fp32 (isb=0)
__device__ __forceinline__ float gload(const void* p, int i, int isb) {
  return isb ? b2f(((const unsigned short*)p)[i]) : ((const float*)p)[i];
}
// monotone bijection float -> uint32 (order-preserving incl. negatives)
__device__ __forceinline__ unsigned tokey(float f) {
  unsigned u = __float_as_uint(f);
  return u ^ (unsigned)(((int)u >> 31) | 0x80000000u);
}

// ---------------- dtype detector (dataset proven fp32; kept for safety) ----------------
__global__ void k_detect(const void* x, int* flag) {
  int tid = threadIdx.x;  // 1 wave
  unsigned short u = ((const unsigned short*)x)[2 * tid];
  int e = (u >> 7) & 0xFF;
  bool sane = (e >= 100 && e <= 140);
  unsigned long long m = __ballot(sane);
  if (tid == 0) *flag = (__popcll(m) >= 40) ? 1 : 0;
}

// ---------------- k_prep: WtF[i][u] = fc1_w[u][i] * (mask<0.5), f32 transposed ----------------
__global__ __launch_bounds__(256) void k_prep(const void* __restrict__ fc1w,
                                              const void* __restrict__ mraw,
                                              float* __restrict__ WtF,
                                              const int* __restrict__ flag) {
  __shared__ float tile[64][65];
  const int isb = *flag;
  const int i0 = blockIdx.x * 64;  // K index (9216)
  const int u0 = blockIdx.y * 64;  // unit index (1024)
  const int tx = threadIdx.x & 63, ty = threadIdx.x >> 6;
  for (int uu = ty; uu < 64; uu += 4) {
    int gi = (u0 + uu) * 9216 + i0 + tx;
    float wv = gload(fc1w, gi, isb);
    float mv = gload(mraw, gi, isb);
    tile[uu][tx] = (mv < 0.5f) ? wv : 0.0f;
  }
  __syncthreads();
  for (int ii = ty; ii < 64; ii += 4)
    WtF[(i0 + ii) * 1024 + u0 + tx] = tile[tx][ii];
}

// ---------------- k_convf: FAST PATH (fp32 input proven by detector) ----------------
// v6 post-mortem of v5: the candidate-bitmask select indexed keys[e] with a
// RUNTIME index (ctzll) -> whole keys[] went to scratch (WRITE_SIZE 13->160MB,
// VGPR 80->76, +90us). Reverted select to the r3-proven static form.
// v6's single change vs r3: the pooled[9216] LDS buffer (36.9KB) is GONE.
// Each thread re-read exactly [tid*36, tid*36+36): 18 values are its own, 18
// come from pair-partner tid^1 (other column-half of the same 72-elem block).
// So pooled == a pairwise 18-float exchange: xbuf[256][19] (odd pad ->
// conflict-free). keep/send picked by static i<3 vs runtime half; fOwn/fOth/
// keys all statically indexed under #pragma unroll (no scratch). Same floats,
// same order => bit-exact. LDS 51.2KB -> 33.6KB: 3 -> 4 blocks/CU to hide the
// barrier-chain latency of the 4-pass radix select.
__global__ __launch_bounds__(256) void k_convf(const float* __restrict__ x,
                                               const float* __restrict__ c1w,
                                               const float* __restrict__ c1b,
                                               const float* __restrict__ duty,
                                               int2* __restrict__ wpair,
                                               int* __restrict__ wcnt,
                                               const int* __restrict__ flag) {
  if (*flag) return;  // bf16 dataset -> fallback kernel handles it
  __shared__ __align__(16) float img[784];
  __shared__ float cw[1600];
  __shared__ float cb[64], bcs[64];
  __shared__ float xbuf[256][19];  // pair-exchange; 19 = 18 + pad (odd stride)
  __shared__ unsigned hist4[4][256];
  __shared__ unsigned wtot[4];
  __shared__ unsigned selb, selk;
  const int tid = threadIdx.x;
  const int b = blockIdx.x;
  const int lane = tid & 63;
  const int wv_id = tid >> 6;

  for (int i = tid; i < 784; i += 256) img[i] = x[b * 784 + i];
  for (int i = tid; i < 1600; i += 256) cw[i] = c1w[i];
  if (tid < 64) {
    cb[tid] = c1b[tid];
    float arg = (float)(400.0 / 9216.0) - duty[tid];
    bcs[tid] = (float)exp((double)arg);
  }
  __syncthreads();

  // mapping: c = tid>>2 (64), half = tid&1 (2), pg = (tid>>1)&1 (2) -> ph0 = pg*6
  float fOwn[18];
  {
    const int c = tid >> 2;
    const int half = tid & 1;
    const int ph0 = ((tid >> 1) & 1) * 6;
    float w[25];
#pragma unroll
    for (int i = 0; i < 25; ++i) w[i] = cw[c * 25 + i];
    const float bias = cb[c];
    float R[6][16];
#pragma unroll
    for (int r = 0; r < 6; ++r) {
      int ir = 2 * ph0 + r;
#pragma unroll
      for (int q = 0; q < 4; ++q)
        ((float4*)&R[r][0])[q] = ((const float4*)img)[ir * 7 + half * 3 + q];
    }
#pragma unroll
    for (int i = 0; i < 6; ++i) {
      const int ph = ph0 + i;
      float a0[12], a1[12];
#pragma unroll
      for (int j = 0; j < 12; ++j) { a0[j] = 0.f; a1[j] = 0.f; }
      // single sequential fmaf chain per conv cell, k = kw*5 + kh order
      // (kh fastest -- Eigen patch linearization) => bit-exact vs reference
#pragma unroll
      for (int kj = 0; kj < 5; ++kj) {       // kw OUTER
#pragma unroll
        for (int kr = 0; kr < 5; ++kr) {     // kh INNER (fastest)
          float wk = w[kr * 5 + kj];
          const float* r0 = &R[(2 * i + kr) % 6][0];
          const float* r1 = &R[(2 * i + kr + 1) % 6][0];
#pragma unroll
          for (int j = 0; j < 12; ++j) {
            a0[j] = fmaf(r0[j + kj], wk, a0[j]);
            a1[j] = fmaf(r1[j + kj], wk, a1[j]);
          }
        }
      }
      // own flat positions this i: p = i*12 + half*6 + q within 72-block.
      // final owner of p is the pair-thread whose half' satisfies i in
      // [3*half', 3*half'+3)  => keep when (i<3) XOR half, else send to tid^1.
#pragma unroll
      for (int q = 0; q < 6; ++q) {
        float m = fmaxf(fmaxf(a0[2 * q], a0[2 * q + 1]),
                        fmaxf(a1[2 * q], a1[2 * q + 1])) + bias;
        if (((i < 3) ? 1 : 0) ^ half)
          fOwn[(i % 3) * 6 + q] = m;      // static index (i%3 const per iter)
        else
          xbuf[tid ^ 1][(i % 3) * 6 + q] = m;
      }
      if (i < 5) {  // slide: load img rows 2*ph+6, 2*ph+7 over the two oldest
        int ir0 = 2 * ph + 6, ir1 = 2 * ph + 7;
        float* d0 = &R[(2 * i) % 6][0];
        float* d1 = &R[(2 * i + 1) % 6][0];
#pragma unroll
        for (int q = 0; q < 4; ++q) {
          ((float4*)d0)[q] = ((const float4*)img)[ir0 * 7 + half * 3 + q];
          ((float4*)d1)[q] = ((const float4*)img)[ir1 * 7 + half * 3 + q];
        }
      }
    }
  }
  __syncthreads();

  const int half = tid & 1;
  float fOth[18];
#pragma unroll
  for (int s = 0; s < 18; ++s) fOth[s] = xbuf[tid][s];  // written by tid^1

  // keys over the thread's contiguous 36: o = tid*36 + e,
  // e = di*12 + hh*6 + q; value = (hh==half) ? fOwn : fOth  (all static idx)
  unsigned keys[36];
  {
    const float bcf = bcs[tid >> 2];
#pragma unroll
    for (int e = 0; e < 36; ++e) {
      const int di = e / 12, hh = (e / 6) % 2, q = e % 6;
      float v = (hh == half) ? fOwn[di * 6 + q] : fOth[di * 6 + q];
      keys[e] = tokey(v * bcf);
    }
  }

  // radix-select the 400th-largest key; per-wave split histograms + shfl suffix scan
  // (r3-proven static form: all 36 keys tested each pass, no runtime indexing)
  unsigned kfix = 0;
  unsigned kk = 400;
  for (int pass = 3; pass >= 0; --pass) {
    const int shift = pass * 8;
    const unsigned himask = (pass == 3) ? 0u : (0xFFFFFFFFu << (shift + 8));
#pragma unroll
    for (int w2 = 0; w2 < 4; ++w2) hist4[w2][tid] = 0;
    __syncthreads();
    unsigned* myh = hist4[wv_id];
#pragma unroll
    for (int e = 0; e < 36; ++e) {
      unsigned key = keys[e];
      if (((key ^ kfix) & himask) == 0)
        atomicAdd(&myh[(key >> shift) & 255u], 1u);
    }
    __syncthreads();
    unsigned own = hist4[0][tid] + hist4[1][tid] + hist4[2][tid] + hist4[3][tid];
    unsigned v = own;
#pragma unroll
    for (int off = 1; off < 64; off <<= 1) {
      unsigned y = __shfl_down(v, off, 64);
      if (lane + off < 64) v += y;
    }
    if (lane == 0) wtot[wv_id] = v;
    __syncthreads();
#pragma unroll
    for (int w2 = 0; w2 < 4; ++w2)
      if (w2 > wv_id) v += wtot[w2];
    unsigned snext = v - own;
    if (v >= kk && snext < kk) {
      selb = (unsigned)tid;
      selk = kk - snext;
    }
    __syncthreads();
    kfix |= selb << shift;
    kk = selk;
    __syncthreads();
  }

  // sorted compaction: per-thread count -> shfl prefix scan -> ordered write.
  // keep ALL with key >= kfix (== boosted >= thr bitwise, ties kept like ref)
  unsigned mycnt = 0;
#pragma unroll
  for (int e = 0; e < 36; ++e) mycnt += (keys[e] >= kfix) ? 1u : 0u;
  unsigned px = mycnt;
#pragma unroll
  for (int off = 1; off < 64; off <<= 1) {
    unsigned y = __shfl_up(px, off, 64);
    if (lane >= off) px += y;
  }
  if (lane == 63) wtot[wv_id] = px;
  __syncthreads();
  unsigned base = 0;
#pragma unroll
  for (int w2 = 0; w2 < 4; ++w2)
    if (w2 < wv_id) base += wtot[w2];
  int pos = (int)(base + px - mycnt);  // exclusive prefix
#pragma unroll
  for (int e = 0; e < 36; ++e) {
    if (keys[e] >= kfix) {
      const int di = e / 12, hh = (e / 6) % 2, q = e % 6;
      float v = (hh == half) ? fOwn[di * 6 + q] : fOth[di * 6 + q];
      int o = tid * 36 + e;
      if (pos < 512)
        wpair[b * 512 + pos] = make_int2(__float_as_int(v), o << 12);
      ++pos;
    }
  }
  if (tid == 0) {
    unsigned tot = wtot[0] + wtot[1] + wtot[2] + wtot[3];
    wcnt[b] = (int)(tot < 512u ? tot : 512u);
  }
}

// ---------------- k_conv: bf16 fallback (gated; dataset proven fp32) ----------------
__global__ __launch_bounds__(256) void k_conv(const void* __restrict__ x,
                                              const void* __restrict__ c1w_g,
                                              const void* __restrict__ c1b_g,
                                              const void* __restrict__ duty_g,
                                              int2* __restrict__ wpair,
                                              int* __restrict__ wcnt,
                                              const int* __restrict__ flag) {
  const int isb = *flag;
  if (!isb) return;  // fast kernel handled it
  __shared__ __align__(16) float img[784];
  __shared__ float cw[1600];
  __shared__ float cb[64], bcs[64];
  __shared__ __align__(16) float pooled[9216];
  __shared__ unsigned hist4[4][256];
  __shared__ unsigned wtot[4];
  __shared__ unsigned selb, selk;
  const int tid = threadIdx.x;
  const int b = blockIdx.x;
  const int lane = tid & 63;
  const int wv_id = tid >> 6;

  for (int i = tid; i < 784; i += 256) img[i] = gload(x, b * 784 + i, isb);
  for (int i = tid; i < 1600; i += 256) cw[i] = gload(c1w_g, i, isb);
  if (tid < 64) {
    cb[tid] = gload(c1b_g, tid, isb);
    float arg = (float)(400.0 / 9216.0) - gload(duty_g, tid, isb);
    bcs[tid] = (float)exp((double)arg);
  }
  __syncthreads();

  {
    const int c = tid >> 2;
    const int half = tid & 1;
    const int ph0 = ((tid >> 1) & 1) * 6;
    float w[25];
#pragma unroll
    for (int i = 0; i < 25; ++i) w[i] = cw[c * 25 + i];
    const float bias = cb[c];
    float R[6][16];
#pragma unroll
    for (int r = 0; r < 6; ++r) {
      int ir = 2 * ph0 + r;
#pragma unroll
      for (int q = 0; q < 4; ++q)
        ((float4*)&R[r][0])[q] = ((const float4*)img)[ir * 7 + half * 3 + q];
    }
#pragma unroll
    for (int i = 0; i < 6; ++i) {
      const int ph = ph0 + i;
      float a0[12], a1[12];
#pragma unroll
      for (int j = 0; j < 12; ++j) { a0[j] = 0.f; a1[j] = 0.f; }
#pragma unroll
      for (int kj = 0; kj < 5; ++kj) {
#pragma unroll
        for (int kr = 0; kr < 5; ++kr) {
          float wk = w[kr * 5 + kj];
          const float* r0 = &R[(2 * i + kr) % 6][0];
          const float* r1 = &R[(2 * i + kr + 1) % 6][0];
#pragma unroll
          for (int j = 0; j < 12; ++j) {
            a0[j] = fmaf(r0[j + kj], wk, a0[j]);
            a1[j] = fmaf(r1[j + kj], wk, a1[j]);
          }
        }
      }
      int obase = c * 144 + ph * 12 + half * 6;
#pragma unroll
      for (int q = 0; q < 6; ++q) {
        float m = fmaxf(fmaxf(a0[2 * q], a0[2 * q + 1]),
                        fmaxf(a1[2 * q], a1[2 * q + 1]));
        pooled[obase + q] = m + bias;
      }
      if (i < 5) {
        int ir0 = 2 * ph + 6, ir1 = 2 * ph + 7;
        float* d0 = &R[(2 * i) % 6][0];
        float* d1 = &R[(2 * i + 1) % 6][0];
#pragma unroll
        for (int q = 0; q < 4; ++q) {
          ((float4*)d0)[q] = ((const float4*)img)[ir0 * 7 + half * 3 + q];
          ((float4*)d1)[q] = ((const float4*)img)[ir1 * 7 + half * 3 + q];
        }
      }
    }
  }
  __syncthreads();

  unsigned keys[36];
  {
    const float bcf = bcs[tid >> 2];
#pragma unroll
    for (int e4 = 0; e4 < 9; ++e4) {
      float4 pv = ((float4*)pooled)[tid * 9 + e4];
      keys[4 * e4 + 0] = tokey(pv.x * bcf);
      keys[4 * e4 + 1] = tokey(pv.y * bcf);
      keys[4 * e4 + 2] = tokey(pv.z * bcf);
      keys[4 * e4 + 3] = tokey(pv.w * bcf);
    }
  }

  unsigned kfix = 0;
  unsigned kk = 400;
  for (int pass = 3; pass >= 0; --pass) {
    const int shift = pass * 8;
    const unsigned himask = (pass == 3) ? 0u : (0xFFFFFFFFu << (shift + 8));
#pragma unroll
    for (int w2 = 0; w2 < 4; ++w2) hist4[w2][tid] = 0;
    __syncthreads();
    unsigned* myh = hist4[wv_id];
#pragma unroll
    for (int e = 0; e < 36; ++e) {
      unsigned key = keys[e];
      if (((key ^ kfix) & himask) == 0)
        atomicAdd(&myh[(key >> shift) & 255u], 1u);
    }
    __syncthreads();
    unsigned own = hist4[0][tid] + hist4[1][tid] + hist4[2][tid] + hist4[3][tid];
    unsigned v = own;
#pragma unroll
    for (int off = 1; off < 64; off <<= 1) {
      unsigned y = __shfl_down(v, off, 64);
      if (lane + off < 64) v += y;
    }
    if (lane == 0) wtot[wv_id] = v;
    __syncthreads();
#pragma unroll
    for (int w2 = 0; w2 < 4; ++w2)
      if (w2 > wv_id) v += wtot[w2];
    unsigned snext = v - own;
    if (v >= kk && snext < kk) {
      selb = (unsigned)tid;
      selk = kk - snext;
    }
    __syncthreads();
    kfix |= selb << shift;
    kk = selk;
    __syncthreads();
  }

  unsigned mycnt = 0;
#pragma unroll
  for (int e = 0; e < 36; ++e) mycnt += (keys[e] >= kfix) ? 1u : 0u;
  unsigned px = mycnt;
#pragma unroll
  for (int off = 1; off < 64; off <<= 1) {
    unsigned y = __shfl_up(px, off, 64);
    if (lane >= off) px += y;
  }
  if (lane == 63) wtot[wv_id] = px;
  __syncthreads();
  unsigned base = 0;
#pragma unroll
  for (int w2 = 0; w2 < 4; ++w2)
    if (w2 < wv_id) base += wtot[w2];
  int pos = (int)(base + px - mycnt);
  for (int e = 0; e < 36; ++e) {
    if (keys[e] >= kfix) {
      int o = tid * 36 + e;
      if (pos < 512)
        wpair[b * 512 + pos] = make_int2(__float_as_int(pooled[o]), o << 12);
      ++pos;
    }
  }
  if (tid == 0) {
    unsigned tot = wtot[0] + wtot[1] + wtot[2] + wtot[3];
    wcnt[b] = (int)(tot < 512u ? tot : 512u);
  }
}

// ---------------- k_fc1: XCD-sliced sparse fc1 gather ----------------
// slice = blockIdx.x & 7 -> consecutive blocks round-robin across the 8 XCDs,
// so each XCD's L2 only sees its 128-unit column slice of WtF (4.7 MB ~ L2).
// LDS-staged winner list; 8-pair unroll via ds_read_b128 so the 8 independent
// global_load_dword issue ahead of the serial fmac chain. Ascending-w single
// f32 fmaf chain per unit => bit-identical h. Half-grid (img_base) x2 for
// rocprof visibility of the other kernels.
__global__ __launch_bounds__(128) void k_fc1(const float* __restrict__ WtF,
                                             const int2* __restrict__ wpair,
                                             const int* __restrict__ wcnt,
                                             const void* __restrict__ fc1b,
                                             float* __restrict__ h,
                                             const int* __restrict__ flag,
                                             int img_base) {
  __shared__ __align__(16) int2 wl[512];
  const int tid = threadIdx.x;  // 0..127
  const int img = img_base + (blockIdx.x >> 3);
  const int slice = blockIdx.x & 7;
  const int isb = *flag;
  const int cnt = wcnt[img];
  const int2* __restrict__ wp = wpair + img * 512;
  for (int i = tid; i < cnt; i += 128) wl[i] = wp[i];
  __syncthreads();
  const int u = (slice << 7) + tid;
  const char* __restrict__ Wb = (const char*)WtF + (unsigned)u * 4u;
  const int4* wl4 = (const int4*)wl;  // 2 pairs per int4, 16B-aligned
  float acc = 0.f;
  int w = 0;
  for (; w + 8 <= cnt; w += 8) {
    const int b4 = w >> 1;
    int4 q0 = wl4[b4 + 0];
    int4 q1 = wl4[b4 + 1];
    int4 q2 = wl4[b4 + 2];
    int4 q3 = wl4[b4 + 3];
    acc = fmaf(__int_as_float(q0.x), *(const float*)(Wb + (unsigned)q0.y), acc);
    acc = fmaf(__int_as_float(q0.z), *(const float*)(Wb + (unsigned)q0.w), acc);
    acc = fmaf(__int_as_float(q1.x), *(const float*)(Wb + (unsigned)q1.y), acc);
    acc = fmaf(__int_as_float(q1.z), *(const float*)(Wb + (unsigned)q1.w), acc);
    acc = fmaf(__int_as_float(q2.x), *(const float*)(Wb + (unsigned)q2.y), acc);
    acc = fmaf(__int_as_float(q2.z), *(const float*)(Wb + (unsigned)q2.w), acc);
    acc = fmaf(__int_as_float(q3.x), *(const float*)(Wb + (unsigned)q3.y), acc);
    acc = fmaf(__int_as_float(q3.z), *(const float*)(Wb + (unsigned)q3.w), acc);
  }
  for (; w < cnt; ++w) {
    int2 p = wl[w];
    acc = fmaf(__int_as_float(p.x), *(const float*)(Wb + (unsigned)p.y), acc);
  }
  h[img * 1024 + u] = acc + gload(fc1b, u, isb);
}

// ---------------- k_boost: fc boost factors computed ONCE ----------------
__global__ __launch_bounds__(256) void k_boost(const void* __restrict__ dutyfc,
                                               float* __restrict__ bf,
                                               const int* __restrict__ flag) {
  const int u = blockIdx.x * 256 + threadIdx.x;
  const int isb = *flag;
  if (u < 1024)
    bf[u] = (float)exp((double)(0.09765625f - gload(dutyfc, u, isb)));
}

// ---------------- k_sel: kwinners(k=100, >=thr) + f64 fc2 + log_softmax ----------------
__global__ __launch_bounds__(256) void k_sel(const float* __restrict__ h,
                                             const float* __restrict__ bf,
                                             const void* __restrict__ fc2w,
                                             const void* __restrict__ fc2b,
                                             void* __restrict__ out,
                                             const int* __restrict__ flag) {
  __shared__ unsigned hist4[4][256];
  __shared__ unsigned wtot[4];
  __shared__ unsigned selb, selk;
  __shared__ double lg[10];
  __shared__ double mred[2];
  const int tid = threadIdx.x;
  const int row = blockIdx.x;
  const int isb = *flag;
  const int lane = tid & 63;
  const int wv_id = tid >> 6;
  if (tid < 10) lg[tid] = (double)gload(fc2b, tid, isb);
  __syncthreads();

  const int u0 = 2 * tid, u1 = 2 * tid + 1, u2 = 512 + 2 * tid, u3 = 513 + 2 * tid;
  float2 hlo = ((const float2*)(h + row * 1024))[tid];
  float2 hhi = ((const float2*)(h + row * 1024 + 512))[tid];
  float h0 = hlo.x, h1 = hlo.y, h2 = hhi.x, h3 = hhi.y;
  float2 blo = ((const float2*)bf)[tid];
  float2 bhi = ((const float2*)(bf + 512))[tid];
  unsigned k0 = tokey(h0 * blo.x);
  unsigned k1 = tokey(h1 * blo.y);
  unsigned k2 = tokey(h2 * bhi.x);
  unsigned k3 = tokey(h3 * bhi.y);

  unsigned kfix = 0;
  unsigned kk = 100;
  for (int pass = 3; pass >= 0; --pass) {
    const int shift = pass * 8;
    const unsigned himask = (pass == 3) ? 0u : (0xFFFFFFFFu << (shift + 8));
#pragma unroll
    for (int w2 = 0; w2 < 4; ++w2) hist4[w2][tid] = 0;
    __syncthreads();
    unsigned* myh = hist4[wv_id];
    if (((k0 ^ kfix) & himask) == 0) atomicAdd(&myh[(k0 >> shift) & 255u], 1u);
    if (((k1 ^ kfix) & himask) == 0) atomicAdd(&myh[(k1 >> shift) & 255u], 1u);
    if (((k2 ^ kfix) & himask) == 0) atomicAdd(&myh[(k2 >> shift) & 255u], 1u);
    if (((k3 ^ kfix) & himask) == 0) atomicAdd(&myh[(k3 >> shift) & 255u], 1u);
    __syncthreads();
    unsigned own = hist4[0][tid] + hist4[1][tid] + hist4[2][tid] + hist4[3][tid];
    unsigned v = own;
#pragma unroll
    for (int off = 1; off < 64; off <<= 1) {
      unsigned y = __shfl_down(v, off, 64);
      if (lane + off < 64) v += y;
    }
    if (lane == 0) wtot[wv_id] = v;
    __syncthreads();
#pragma unroll
    for (int w2 = 0; w2 < 4; ++w2)
      if (w2 > wv_id) v += wtot[w2];
    unsigned snext = v - own;
    if (v >= kk && snext < kk) {
      selb = (unsigned)tid;
      selk = kk - snext;
    }
    __syncthreads();
    kfix |= selb << shift;
    kk = selk;
    __syncthreads();
  }
  bool kp0 = k0 >= kfix, kp1 = k1 >= kfix, kp2 = k2 >= kfix, kp3 = k3 >= kfix;

  double part[10];
#pragma unroll
  for (int c = 0; c < 10; ++c) part[c] = 0.0;
  if (kp0) {
#pragma unroll
    for (int c = 0; c < 10; ++c) part[c] = fma((double)h0, (double)gload(fc2w, c * 1024 + u0, isb), part[c]);
  }
  if (kp1) {
#pragma unroll
    for (int c = 0; c < 10; ++c) part[c] = fma((double)h1, (double)gload(fc2w, c * 1024 + u1, isb), part[c]);
  }
  if (kp2) {
#pragma unroll
    for (int c = 0; c < 10; ++c) part[c] = fma((double)h2, (double)gload(fc2w, c * 1024 + u2, isb), part[c]);
  }
  if (kp3) {
#pragma unroll
    for (int c = 0; c < 10; ++c) part[c] = fma((double)h3, (double)gload(fc2w, c * 1024 + u3, isb), part[c]);
  }
#pragma unroll
  for (int c = 0; c < 10; ++c) {
    double p = part[c];
    for (int off = 32; off > 0; off >>= 1) p += __shfl_xor(p, off);
    if ((tid & 63) == 0) atomicAdd(&lg[c], p);
  }
  __syncthreads();
  if (tid == 0) {
    double m = lg[0];
#pragma unroll
    for (int c = 1; c < 10; ++c) m = lg[c] > m ? lg[c] : m;
    double sum = 0.0;
#pragma unroll
    for (int c = 0; c < 10; ++c) sum += exp(lg[c] - m);
    mred[0] = m;
    mred[1] = log(sum);
  }
  __syncthreads();
  if (tid < 10) {
    double o = lg[tid] - mred[0] - mred[1];
    if (isb)
      ((unsigned short*)out)[row * 10 + tid] = f2b((float)o);
    else
      ((float*)out)[row * 10 + tid] = (float)o;
  }
}

// ---------------- launch ----------------
extern "C" void kernel_launch(void* const* d_in, const int* in_sizes, int n_in,
                              void* d_out, int out_size, void* d_ws, size_t ws_size,
                              hipStream_t stream) {
  // ws layout (bytes):
  //   WtF   : 9216*1024*4 = 37,748,736  @ 0   (reused as bf[1024] after k_fc1)
  //   wpair : 4096*512*8  = 16,777,216  @ 37,748,736
  //   wcnt  : 4096*4      =     16,384  @ 54,525,952
  //   h     : 4096*1024*4 = 16,777,216  @ 54,542,336
  //   flag  : 4                         @ 71,319,552
  char* ws = (char*)d_ws;
  float* WtF = (float*)ws;
  int2* wpair = (int2*)(ws + 37748736);
  int* wcnt = (int*)(ws + 54525952);
  float* h = (float*)(ws + 54542336);
  int* flag = (int*)(ws + 71319552);
  float* bf = WtF;  // WtF region is dead after k_fc1

  k_detect<<<1, 64, 0, stream>>>(d_in[0], flag);
  k_prep<<<dim3(144, 16), 256, 0, stream>>>(d_in[4], d_in[5], WtF, flag);
  k_convf<<<4096, 256, 0, stream>>>((const float*)d_in[0], (const float*)d_in[1],
                                    (const float*)d_in[2], (const float*)d_in[3],
                                    wpair, wcnt, flag);
  k_conv<<<4096, 256, 0, stream>>>(d_in[0], d_in[1], d_in[2], d_in[3],
                                   wpair, wcnt, flag);
  k_fc1<<<2048 * 8, 128, 0, stream>>>(WtF, wpair, wcnt, d_in[6], h, flag, 0);
  k_fc1<<<2048 * 8, 128, 0, stream>>>(WtF, wpair, wcnt, d_in[6], h, flag, 2048);
  k_boost<<<4, 256, 0, stream>>>(d_in[7], bf, flag);
  k_sel<<<4096, 256, 0, stream>>>(h, bf, d_in[8], d_in[9], d_out, flag);
}